// Round 1
// baseline (1827.071 us; speedup 1.0000x reference)
//
#include <hip/hip_runtime.h>

// Problem constants (from reference setup_inputs)
#define FDIM 500
#define H1DIM 128
#define H2DIM 64
#define CDIM 10

// ---------------------------------------------------------------------------
// CSR build: histogram of dst -> counts; two-level exclusive scan -> row_ptr;
// atomic-cursor fill -> col (list of src per dst). dis = rsqrt(deg+1).
// ---------------------------------------------------------------------------

__global__ __launch_bounds__(256) void hist_kernel(const int* __restrict__ dst,
                                                   int* __restrict__ cnt, int E) {
    int e = blockIdx.x * 256 + threadIdx.x;
    if (e < E) atomicAdd(&cnt[dst[e]], 1);
}

__global__ __launch_bounds__(256) void dis_kernel(const int* __restrict__ cnt,
                                                  float* __restrict__ dis, int n) {
    int i = blockIdx.x * 256 + threadIdx.x;
    if (i < n) dis[i] = rsqrtf((float)cnt[i] + 1.0f);  // +1 self loop
}

__global__ __launch_bounds__(256) void block_reduce_kernel(const int* __restrict__ cnt,
                                                           int* __restrict__ bsums, int n) {
    __shared__ int s[256];
    int i = blockIdx.x * 256 + threadIdx.x;
    s[threadIdx.x] = (i < n) ? cnt[i] : 0;
    __syncthreads();
    for (int o = 128; o > 0; o >>= 1) {
        if (threadIdx.x < o) s[threadIdx.x] += s[threadIdx.x + o];
        __syncthreads();
    }
    if (threadIdx.x == 0) bsums[blockIdx.x] = s[0];
}

// single block of 512 threads: exclusive scan of bsums (nb <= 512), total -> row_ptr[n]
__global__ __launch_bounds__(512) void scan_sums_kernel(int* __restrict__ bsums, int nb,
                                                        int* __restrict__ row_ptr, int n) {
    __shared__ int s[512];
    int v = (threadIdx.x < nb) ? bsums[threadIdx.x] : 0;
    s[threadIdx.x] = v;
    __syncthreads();
    for (int o = 1; o < 512; o <<= 1) {
        int t = (threadIdx.x >= o) ? s[threadIdx.x - o] : 0;
        __syncthreads();
        s[threadIdx.x] += t;
        __syncthreads();
    }
    if (threadIdx.x < nb) bsums[threadIdx.x] = s[threadIdx.x] - v;  // exclusive
    if (threadIdx.x == 511) row_ptr[n] = s[511];                    // total == E
}

// per-block scan of counts + block offset -> row_ptr and cursor (cursor aliases cnt: safe,
// each thread reads its own element into LDS before overwriting it)
__global__ __launch_bounds__(256) void scan_blocks_kernel(const int* __restrict__ cnt,
                                                          const int* __restrict__ bsums,
                                                          int* __restrict__ row_ptr,
                                                          int* __restrict__ cursor, int n) {
    __shared__ int s[256];
    int i = blockIdx.x * 256 + threadIdx.x;
    int v = (i < n) ? cnt[i] : 0;
    s[threadIdx.x] = v;
    __syncthreads();
    for (int o = 1; o < 256; o <<= 1) {
        int t = (threadIdx.x >= o) ? s[threadIdx.x - o] : 0;
        __syncthreads();
        s[threadIdx.x] += t;
        __syncthreads();
    }
    int excl = s[threadIdx.x] - v + bsums[blockIdx.x];
    if (i < n) {
        row_ptr[i] = excl;
        cursor[i] = excl;
    }
}

__global__ __launch_bounds__(256) void fill_kernel(const int* __restrict__ src,
                                                   const int* __restrict__ dst,
                                                   int* __restrict__ cursor,
                                                   int* __restrict__ col, int E) {
    int e = blockIdx.x * 256 + threadIdx.x;
    if (e < E) {
        int d = dst[e];
        int pos = atomicAdd(&cursor[d], 1);
        col[pos] = src[e];
    }
}

// ---------------------------------------------------------------------------
// fp32 GEMM: C[M x N_] = A[M x K] * B[K x N_]. Register tile: TM rows/thread,
// float4 over K. Requires M % ((256/N_)*TM) == 0, K % 4 == 0.
// ---------------------------------------------------------------------------
template <int N_, int TM>
__global__ __launch_bounds__(256) void gemm_kernel(const float* __restrict__ A,
                                                   const float* __restrict__ B,
                                                   float* __restrict__ C, int M, int K) {
    constexpr int RG = 256 / N_;
    const int n = threadIdx.x % N_;
    const int mg = threadIdx.x / N_;
    const int m0 = blockIdx.x * (RG * TM) + mg * TM;

    float acc[TM];
#pragma unroll
    for (int i = 0; i < TM; i++) acc[i] = 0.f;

    const float4* Arows[TM];
#pragma unroll
    for (int i = 0; i < TM; i++) Arows[i] = (const float4*)(A + (size_t)(m0 + i) * K);

    const int K4 = K / 4;
    const float* Bn = B + n;
    for (int k4 = 0; k4 < K4; k4++) {
        const float* Bk = Bn + (size_t)(k4 * 4) * N_;
        float b0 = Bk[0];
        float b1 = Bk[N_];
        float b2 = Bk[2 * N_];
        float b3 = Bk[3 * N_];
#pragma unroll
        for (int i = 0; i < TM; i++) {
            float4 a = Arows[i][k4];
            acc[i] = fmaf(a.x, b0, acc[i]);
            acc[i] = fmaf(a.y, b1, acc[i]);
            acc[i] = fmaf(a.z, b2, acc[i]);
            acc[i] = fmaf(a.w, b3, acc[i]);
        }
    }
#pragma unroll
    for (int i = 0; i < TM; i++) C[(size_t)(m0 + i) * N_ + n] = acc[i];
}

// ---------------------------------------------------------------------------
// GCN aggregation (gather form): out[i] = relu( sum_{e:dst=i} dis[i]*dis[src]*h[src]
//                                             + dis[i]^2 * h[i] + bias )
// One wave per node. D=128 -> float2/lane; D=64 -> float/lane.
// ---------------------------------------------------------------------------
template <int D>
__global__ __launch_bounds__(256) void aggregate_kernel(const float* __restrict__ h,
                                                        const float* __restrict__ dis,
                                                        const int* __restrict__ row_ptr,
                                                        const int* __restrict__ col,
                                                        const float* __restrict__ bias,
                                                        float* __restrict__ out, int n) {
    const int node = blockIdx.x * 4 + (threadIdx.x >> 6);
    const int lane = threadIdx.x & 63;
    if (node >= n) return;
    const float di = dis[node];
    const int beg = row_ptr[node];
    const int end = row_ptr[node + 1];

    if (D == 128) {
        const float2* hp = (const float2*)h;  // row = 64 float2
        float2 hv = hp[(size_t)node * 64 + lane];
        float wself = di * di;
        float ax = wself * hv.x, ay = wself * hv.y;
        for (int j = beg; j < end; j++) {
            int s = col[j];
            float w = di * dis[s];
            float2 v = hp[(size_t)s * 64 + lane];
            ax = fmaf(w, v.x, ax);
            ay = fmaf(w, v.y, ay);
        }
        float2 r;
        r.x = fmaxf(ax + bias[2 * lane], 0.f);
        r.y = fmaxf(ay + bias[2 * lane + 1], 0.f);
        ((float2*)out)[(size_t)node * 64 + lane] = r;
    } else {
        float acc = di * di * h[(size_t)node * D + lane];
        for (int j = beg; j < end; j++) {
            int s = col[j];
            acc = fmaf(di * dis[s], h[(size_t)s * D + lane], acc);
        }
        out[(size_t)node * D + lane] = fmaxf(acc + bias[lane], 0.f);
    }
}

// ---------------------------------------------------------------------------
// classifier: out[M x 10] = A[M x 64] * Wc[64 x 10] + bc. 16 threads/row (6 idle).
// ---------------------------------------------------------------------------
__global__ __launch_bounds__(256) void classifier_kernel(const float* __restrict__ A,
                                                         const float* __restrict__ Wc,
                                                         const float* __restrict__ bc,
                                                         float* __restrict__ out, int M) {
    int idx = blockIdx.x * 256 + threadIdx.x;
    int row = idx >> 4;
    int c = idx & 15;
    if (row >= M || c >= CDIM) return;
    const float* a = A + (size_t)row * H2DIM;
    float acc = bc[c];
#pragma unroll 8
    for (int k = 0; k < H2DIM; k++) acc = fmaf(a[k], Wc[k * CDIM + c], acc);
    out[(size_t)row * CDIM + c] = acc;
}

// ---------------------------------------------------------------------------

extern "C" void kernel_launch(void* const* d_in, const int* in_sizes, int n_in,
                              void* d_out, int out_size, void* d_ws, size_t ws_size,
                              hipStream_t stream) {
    const float* x  = (const float*)d_in[0];
    const int*   ei = (const int*)d_in[1];
    const float* W1 = (const float*)d_in[2];
    const float* b1 = (const float*)d_in[3];
    const float* W2 = (const float*)d_in[4];
    const float* b2 = (const float*)d_in[5];
    const float* Wc = (const float*)d_in[6];
    const float* bc = (const float*)d_in[7];
    float* out = (float*)d_out;

    const int N = in_sizes[0] / FDIM;      // 100000
    const int E = in_sizes[1] / 2;         // 1600000
    const int* src = ei;
    const int* dst = ei + E;

    // workspace layout (bytes)
    char* ws = (char*)d_ws;
    int*   cnt    = (int*)(ws + 0x0);          // N ints; reused as cursor after scan
    int*   rowptr = (int*)(ws + 0x80000);      // N+1 ints
    float* dis    = (float*)(ws + 0x100000);   // N floats
    int*   bsums  = (int*)(ws + 0x180000);     // ceil(N/256) ints
    int*   col    = (int*)(ws + 0x200000);     // E ints (6.4 MB)
    float* bufA   = (float*)(ws + 0xA00000);   // N*128 fp32 (51.2 MB)
    float* bufB   = (float*)(ws + 0xA00000 + 0x3400000);  // N*128 fp32

    const int nb = (N + 255) / 256;  // 391

    // 1. CSR build + dis
    hipMemsetAsync(cnt, 0, (size_t)N * sizeof(int), stream);
    hist_kernel<<<(E + 255) / 256, 256, 0, stream>>>(dst, cnt, E);
    dis_kernel<<<nb, 256, 0, stream>>>(cnt, dis, N);
    block_reduce_kernel<<<nb, 256, 0, stream>>>(cnt, bsums, N);
    scan_sums_kernel<<<1, 512, 0, stream>>>(bsums, nb, rowptr, N);
    scan_blocks_kernel<<<nb, 256, 0, stream>>>(cnt, bsums, rowptr, /*cursor=*/cnt, N);
    fill_kernel<<<(E + 255) / 256, 256, 0, stream>>>(src, dst, /*cursor=*/cnt, col, E);

    // 2. layer 1: h1 = x @ W1 ; agg1 = relu(aggregate(h1) + b1)
    gemm_kernel<H1DIM, 4><<<N / 8, 256, 0, stream>>>(x, W1, bufA, N, FDIM);
    aggregate_kernel<H1DIM><<<(N + 3) / 4, 256, 0, stream>>>(bufA, dis, rowptr, col, b1, bufB, N);

    // 3. layer 2: h2 = agg1 @ W2 ; agg2 = relu(aggregate(h2) + b2)
    gemm_kernel<H2DIM, 4><<<N / 16, 256, 0, stream>>>(bufB, W2, bufA, N, H1DIM);
    aggregate_kernel<H2DIM><<<(N + 3) / 4, 256, 0, stream>>>(bufA, dis, rowptr, col, b2, bufB, N);

    // 4. classifier
    classifier_kernel<<<(N * 16 + 255) / 256, 256, 0, stream>>>(bufB, Wc, bc, out, N);
}

// Round 2
// 993.172 us; speedup vs baseline: 1.8396x; 1.8396x over previous
//
#include <hip/hip_runtime.h>

// Problem constants (from reference setup_inputs)
#define FDIM 500
#define H1DIM 128
#define H2DIM 64
#define CDIM 10

// ---------------------------------------------------------------------------
// CSR build: histogram of dst -> counts; two-level exclusive scan -> row_ptr;
// atomic-cursor fill -> col (list of src per dst). dis = rsqrt(deg+1).
// ---------------------------------------------------------------------------

__global__ __launch_bounds__(256) void hist_kernel(const int* __restrict__ dst,
                                                   int* __restrict__ cnt, int E) {
    int e = blockIdx.x * 256 + threadIdx.x;
    if (e < E) atomicAdd(&cnt[dst[e]], 1);
}

__global__ __launch_bounds__(256) void dis_kernel(const int* __restrict__ cnt,
                                                  float* __restrict__ dis, int n) {
    int i = blockIdx.x * 256 + threadIdx.x;
    if (i < n) dis[i] = rsqrtf((float)cnt[i] + 1.0f);  // +1 self loop
}

__global__ __launch_bounds__(256) void block_reduce_kernel(const int* __restrict__ cnt,
                                                           int* __restrict__ bsums, int n) {
    __shared__ int s[256];
    int i = blockIdx.x * 256 + threadIdx.x;
    s[threadIdx.x] = (i < n) ? cnt[i] : 0;
    __syncthreads();
    for (int o = 128; o > 0; o >>= 1) {
        if (threadIdx.x < o) s[threadIdx.x] += s[threadIdx.x + o];
        __syncthreads();
    }
    if (threadIdx.x == 0) bsums[blockIdx.x] = s[0];
}

// single block of 512 threads: exclusive scan of bsums (nb <= 512), total -> row_ptr[n]
__global__ __launch_bounds__(512) void scan_sums_kernel(int* __restrict__ bsums, int nb,
                                                        int* __restrict__ row_ptr, int n) {
    __shared__ int s[512];
    int v = (threadIdx.x < nb) ? bsums[threadIdx.x] : 0;
    s[threadIdx.x] = v;
    __syncthreads();
    for (int o = 1; o < 512; o <<= 1) {
        int t = (threadIdx.x >= o) ? s[threadIdx.x - o] : 0;
        __syncthreads();
        s[threadIdx.x] += t;
        __syncthreads();
    }
    if (threadIdx.x < nb) bsums[threadIdx.x] = s[threadIdx.x] - v;  // exclusive
    if (threadIdx.x == 511) row_ptr[n] = s[511];                    // total == E
}

// per-block scan of counts + block offset -> row_ptr and cursor (cursor aliases cnt: safe,
// each thread reads its own element into LDS before overwriting it)
__global__ __launch_bounds__(256) void scan_blocks_kernel(const int* __restrict__ cnt,
                                                          const int* __restrict__ bsums,
                                                          int* __restrict__ row_ptr,
                                                          int* __restrict__ cursor, int n) {
    __shared__ int s[256];
    int i = blockIdx.x * 256 + threadIdx.x;
    int v = (i < n) ? cnt[i] : 0;
    s[threadIdx.x] = v;
    __syncthreads();
    for (int o = 1; o < 256; o <<= 1) {
        int t = (threadIdx.x >= o) ? s[threadIdx.x - o] : 0;
        __syncthreads();
        s[threadIdx.x] += t;
        __syncthreads();
    }
    int excl = s[threadIdx.x] - v + bsums[blockIdx.x];
    if (i < n) {
        row_ptr[i] = excl;
        cursor[i] = excl;
    }
}

__global__ __launch_bounds__(256) void fill_kernel(const int* __restrict__ src,
                                                   const int* __restrict__ dst,
                                                   int* __restrict__ cursor,
                                                   int* __restrict__ col, int E) {
    int e = blockIdx.x * 256 + threadIdx.x;
    if (e < E) {
        int d = dst[e];
        int pos = atomicAdd(&cursor[d], 1);
        col[pos] = src[e];
    }
}

// ---------------------------------------------------------------------------
// Tiled fp32 GEMM: C[M x BN] = A[M x K] * B[K x BN], BN in {128, 64}.
// Block tile BM=128 x BN, KT=16; 256 threads; thread tile 8 x (BN/16).
// LDS: As[KT][BM+4] (pad -> 2-way conflict = free), Bs[KT][BN].
// M-tail: clamped loads + guarded stores. K-tail: zero-padded LDS.
// ---------------------------------------------------------------------------
template <int BN>
__global__ __launch_bounds__(256) void gemm_tiled(const float* __restrict__ A,
                                                  const float* __restrict__ B,
                                                  float* __restrict__ C, int M, int K) {
    constexpr int BM = 128, KT = 16, TM = 8, TN = BN / 16;
    constexpr int AS = BM + 4;
    __shared__ float As[KT][AS];
    __shared__ float Bs[KT][BN];

    const int tid = threadIdx.x;
    const int mf = tid & 15;   // 0..15 -> rows mf*8..+7
    const int nf = tid >> 4;   // 0..15 -> cols nf*TN..+TN-1
    const int m0 = blockIdx.x * BM;

    // A loader: lrow (0..63, +64), lc (0..3): float4 at A[m0+lrow][k0+lc*4]
    const int lrow = tid >> 2;
    const int lc = tid & 3;
    // B loader
    const int bn4 = (BN == 128) ? (tid & 31) : (tid & 15);  // float4 col
    const int blr = (BN == 128) ? (tid >> 5) : (tid >> 4);  // row (0..7 +8) or (0..15)

    float acc[TM][TN];
#pragma unroll
    for (int i = 0; i < TM; i++)
#pragma unroll
        for (int j = 0; j < TN; j++) acc[i][j] = 0.f;

    const int ar0 = min(m0 + lrow, M - 1);       // clamped: dup loads, stores guarded
    const int ar1 = min(m0 + lrow + 64, M - 1);
    const int nkt = (K + KT - 1) / KT;

    for (int t = 0; t < nkt; t++) {
        const int k0 = t * KT;
        // ---- load A tile (2 float4/thread), zero-pad K tail (K%4==0 assumed) ----
        float4 a0 = make_float4(0.f, 0.f, 0.f, 0.f), a1 = a0;
        if (k0 + lc * 4 < K) {
            a0 = *(const float4*)(A + (size_t)ar0 * K + k0 + lc * 4);
            a1 = *(const float4*)(A + (size_t)ar1 * K + k0 + lc * 4);
        }
        // ---- load B tile ----
        float4 b0 = make_float4(0.f, 0.f, 0.f, 0.f), b1 = b0;
        if (BN == 128) {
            if (k0 + blr < K)      b0 = *(const float4*)(B + (size_t)(k0 + blr) * BN + bn4 * 4);
            if (k0 + blr + 8 < K)  b1 = *(const float4*)(B + (size_t)(k0 + blr + 8) * BN + bn4 * 4);
        } else {
            if (k0 + blr < K)      b0 = *(const float4*)(B + (size_t)(k0 + blr) * BN + bn4 * 4);
        }
        __syncthreads();
        As[lc * 4 + 0][lrow] = a0.x;  As[lc * 4 + 1][lrow] = a0.y;
        As[lc * 4 + 2][lrow] = a0.z;  As[lc * 4 + 3][lrow] = a0.w;
        As[lc * 4 + 0][lrow + 64] = a1.x;  As[lc * 4 + 1][lrow + 64] = a1.y;
        As[lc * 4 + 2][lrow + 64] = a1.z;  As[lc * 4 + 3][lrow + 64] = a1.w;
        *(float4*)&Bs[blr][bn4 * 4] = b0;
        if (BN == 128) *(float4*)&Bs[blr + 8][bn4 * 4] = b1;
        __syncthreads();

        // ---- compute ----
#pragma unroll
        for (int k = 0; k < KT; k++) {
            float a[TM], b[TN];
            *(float4*)&a[0] = *(const float4*)&As[k][mf * TM];
            *(float4*)&a[4] = *(const float4*)&As[k][mf * TM + 4];
            *(float4*)&b[0] = *(const float4*)&Bs[k][nf * TN];
            if (TN == 8) *(float4*)&b[4] = *(const float4*)&Bs[k][nf * TN + 4];
#pragma unroll
            for (int i = 0; i < TM; i++)
#pragma unroll
                for (int j = 0; j < TN; j++) acc[i][j] = fmaf(a[i], b[j], acc[i][j]);
        }
    }

    // ---- store ----
#pragma unroll
    for (int i = 0; i < TM; i++) {
        const int row = m0 + mf * TM + i;
        if (row < M) {
#pragma unroll
            for (int j = 0; j < TN; j += 4) {
                *(float4*)(C + (size_t)row * BN + nf * TN + j) = *(const float4*)&acc[i][j];
            }
        }
    }
}

// ---------------------------------------------------------------------------
// GCN aggregation (gather form): out[i] = relu( sum_{e:dst=i} dis[i]*dis[src]*h[src]
//                                             + dis[i]^2 * h[i] + bias )
// One wave per node. D=128 -> float2/lane; D=64 -> float/lane.
// ---------------------------------------------------------------------------
template <int D>
__global__ __launch_bounds__(256) void aggregate_kernel(const float* __restrict__ h,
                                                        const float* __restrict__ dis,
                                                        const int* __restrict__ row_ptr,
                                                        const int* __restrict__ col,
                                                        const float* __restrict__ bias,
                                                        float* __restrict__ out, int n) {
    const int node = blockIdx.x * 4 + (threadIdx.x >> 6);
    const int lane = threadIdx.x & 63;
    if (node >= n) return;
    const float di = dis[node];
    const int beg = row_ptr[node];
    const int end = row_ptr[node + 1];

    if (D == 128) {
        const float2* hp = (const float2*)h;  // row = 64 float2
        float2 hv = hp[(size_t)node * 64 + lane];
        float wself = di * di;
        float ax = wself * hv.x, ay = wself * hv.y;
        for (int j = beg; j < end; j++) {
            int s = col[j];
            float w = di * dis[s];
            float2 v = hp[(size_t)s * 64 + lane];
            ax = fmaf(w, v.x, ax);
            ay = fmaf(w, v.y, ay);
        }
        float2 r;
        r.x = fmaxf(ax + bias[2 * lane], 0.f);
        r.y = fmaxf(ay + bias[2 * lane + 1], 0.f);
        ((float2*)out)[(size_t)node * 64 + lane] = r;
    } else {
        float acc = di * di * h[(size_t)node * D + lane];
        for (int j = beg; j < end; j++) {
            int s = col[j];
            acc = fmaf(di * dis[s], h[(size_t)s * D + lane], acc);
        }
        out[(size_t)node * D + lane] = fmaxf(acc + bias[lane], 0.f);
    }
}

// ---------------------------------------------------------------------------
// classifier: out[M x 10] = A[M x 64] * Wc[64 x 10] + bc. 16 threads/row (6 idle).
// ---------------------------------------------------------------------------
__global__ __launch_bounds__(256) void classifier_kernel(const float* __restrict__ A,
                                                         const float* __restrict__ Wc,
                                                         const float* __restrict__ bc,
                                                         float* __restrict__ out, int M) {
    int idx = blockIdx.x * 256 + threadIdx.x;
    int row = idx >> 4;
    int c = idx & 15;
    if (row >= M || c >= CDIM) return;
    const float* a = A + (size_t)row * H2DIM;
    float acc = bc[c];
#pragma unroll 8
    for (int k = 0; k < H2DIM; k++) acc = fmaf(a[k], Wc[k * CDIM + c], acc);
    out[(size_t)row * CDIM + c] = acc;
}

// ---------------------------------------------------------------------------

extern "C" void kernel_launch(void* const* d_in, const int* in_sizes, int n_in,
                              void* d_out, int out_size, void* d_ws, size_t ws_size,
                              hipStream_t stream) {
    const float* x  = (const float*)d_in[0];
    const int*   ei = (const int*)d_in[1];
    const float* W1 = (const float*)d_in[2];
    const float* b1 = (const float*)d_in[3];
    const float* W2 = (const float*)d_in[4];
    const float* b2 = (const float*)d_in[5];
    const float* Wc = (const float*)d_in[6];
    const float* bc = (const float*)d_in[7];
    float* out = (float*)d_out;

    const int N = in_sizes[0] / FDIM;      // 100000
    const int E = in_sizes[1] / 2;         // 1600000
    const int* src = ei;
    const int* dst = ei + E;

    // workspace layout (bytes)
    char* ws = (char*)d_ws;
    int*   cnt    = (int*)(ws + 0x0);          // N ints; reused as cursor after scan
    int*   rowptr = (int*)(ws + 0x80000);      // N+1 ints
    float* dis    = (float*)(ws + 0x100000);   // N floats
    int*   bsums  = (int*)(ws + 0x180000);     // ceil(N/256) ints
    int*   col    = (int*)(ws + 0x200000);     // E ints (6.4 MB)
    float* bufA   = (float*)(ws + 0xA00000);   // N*128 fp32 (51.2 MB)
    float* bufB   = (float*)(ws + 0xA00000 + 0x3400000);  // N*128 fp32

    const int nb = (N + 255) / 256;  // 391

    // 1. CSR build + dis
    hipMemsetAsync(cnt, 0, (size_t)N * sizeof(int), stream);
    hist_kernel<<<(E + 255) / 256, 256, 0, stream>>>(dst, cnt, E);
    dis_kernel<<<nb, 256, 0, stream>>>(cnt, dis, N);
    block_reduce_kernel<<<nb, 256, 0, stream>>>(cnt, bsums, N);
    scan_sums_kernel<<<1, 512, 0, stream>>>(bsums, nb, rowptr, N);
    scan_blocks_kernel<<<nb, 256, 0, stream>>>(cnt, bsums, rowptr, /*cursor=*/cnt, N);
    fill_kernel<<<(E + 255) / 256, 256, 0, stream>>>(src, dst, /*cursor=*/cnt, col, E);

    const int gblocks = (N + 127) / 128;  // 782

    // 2. layer 1: h1 = x @ W1 ; agg1 = relu(aggregate(h1) + b1)
    gemm_tiled<H1DIM><<<gblocks, 256, 0, stream>>>(x, W1, bufA, N, FDIM);
    aggregate_kernel<H1DIM><<<(N + 3) / 4, 256, 0, stream>>>(bufA, dis, rowptr, col, b1, bufB, N);

    // 3. layer 2: h2 = agg1 @ W2 ; agg2 = relu(aggregate(h2) + b2)
    gemm_tiled<H2DIM><<<gblocks, 256, 0, stream>>>(bufB, W2, bufA, N, H1DIM);
    aggregate_kernel<H2DIM><<<(N + 3) / 4, 256, 0, stream>>>(bufA, dis, rowptr, col, b2, bufB, N);

    // 4. classifier
    classifier_kernel<<<(N * 16 + 255) / 256, 256, 0, stream>>>(bufB, Wc, bc, out, N);
}

// Round 3
// 910.082 us; speedup vs baseline: 2.0076x; 1.0913x over previous
//
#include <hip/hip_runtime.h>

// Problem constants (from reference setup_inputs)
#define FDIM 500
#define H1DIM 128
#define H2DIM 64
#define CDIM 10

using f32x4 = __attribute__((ext_vector_type(4))) float;
using bf16x8 = __attribute__((ext_vector_type(8))) short;  // 8 bf16 in 4 VGPRs

__device__ __forceinline__ unsigned short f32_to_bf16(float f) {
    unsigned u = __builtin_bit_cast(unsigned, f);
    u += 0x7FFFu + ((u >> 16) & 1u);  // RNE (inputs are finite, no NaN handling)
    return (unsigned short)(u >> 16);
}
__device__ __forceinline__ float bf16_to_f32(unsigned short h) {
    return __builtin_bit_cast(float, (unsigned)h << 16);
}

// ---------------------------------------------------------------------------
// CSR build: histogram -> two-level scan -> atomic-cursor fill. dis = rsqrt(deg+1).
// ---------------------------------------------------------------------------

__global__ __launch_bounds__(256) void hist_kernel(const int* __restrict__ dst,
                                                   int* __restrict__ cnt, int E) {
    int e = blockIdx.x * 256 + threadIdx.x;
    if (e < E) atomicAdd(&cnt[dst[e]], 1);
}

__global__ __launch_bounds__(256) void dis_kernel(const int* __restrict__ cnt,
                                                  float* __restrict__ dis, int n) {
    int i = blockIdx.x * 256 + threadIdx.x;
    if (i < n) dis[i] = rsqrtf((float)cnt[i] + 1.0f);  // +1 self loop
}

__global__ __launch_bounds__(256) void block_reduce_kernel(const int* __restrict__ cnt,
                                                           int* __restrict__ bsums, int n) {
    __shared__ int s[256];
    int i = blockIdx.x * 256 + threadIdx.x;
    s[threadIdx.x] = (i < n) ? cnt[i] : 0;
    __syncthreads();
    for (int o = 128; o > 0; o >>= 1) {
        if (threadIdx.x < o) s[threadIdx.x] += s[threadIdx.x + o];
        __syncthreads();
    }
    if (threadIdx.x == 0) bsums[blockIdx.x] = s[0];
}

__global__ __launch_bounds__(512) void scan_sums_kernel(int* __restrict__ bsums, int nb,
                                                        int* __restrict__ row_ptr, int n) {
    __shared__ int s[512];
    int v = (threadIdx.x < nb) ? bsums[threadIdx.x] : 0;
    s[threadIdx.x] = v;
    __syncthreads();
    for (int o = 1; o < 512; o <<= 1) {
        int t = (threadIdx.x >= o) ? s[threadIdx.x - o] : 0;
        __syncthreads();
        s[threadIdx.x] += t;
        __syncthreads();
    }
    if (threadIdx.x < nb) bsums[threadIdx.x] = s[threadIdx.x] - v;  // exclusive
    if (threadIdx.x == 511) row_ptr[n] = s[511];                    // total == E
}

__global__ __launch_bounds__(256) void scan_blocks_kernel(const int* __restrict__ cnt,
                                                          const int* __restrict__ bsums,
                                                          int* __restrict__ row_ptr,
                                                          int* __restrict__ cursor, int n) {
    __shared__ int s[256];
    int i = blockIdx.x * 256 + threadIdx.x;
    int v = (i < n) ? cnt[i] : 0;
    s[threadIdx.x] = v;
    __syncthreads();
    for (int o = 1; o < 256; o <<= 1) {
        int t = (threadIdx.x >= o) ? s[threadIdx.x - o] : 0;
        __syncthreads();
        s[threadIdx.x] += t;
        __syncthreads();
    }
    int excl = s[threadIdx.x] - v + bsums[blockIdx.x];
    if (i < n) {
        row_ptr[i] = excl;
        cursor[i] = excl;
    }
}

__global__ __launch_bounds__(256) void fill_kernel(const int* __restrict__ src,
                                                   const int* __restrict__ dst,
                                                   int* __restrict__ cursor,
                                                   int* __restrict__ col, int E) {
    int e = blockIdx.x * 256 + threadIdx.x;
    if (e < E) {
        int d = dst[e];
        int pos = atomicAdd(&cursor[d], 1);
        col[pos] = src[e];
    }
}

// ---------------------------------------------------------------------------
// Pre-pack W (fp32 [K,N]) into MFMA B-fragment layout, bf16, K zero-padded to
// T = ceil(K/32) tiles. Element Bp[((t*NF+nf)*64+l)*8+j] = W[t*32+(l>>4)*8+j][nf*16+(l&15)]
// ---------------------------------------------------------------------------
__global__ __launch_bounds__(256) void pack_w_kernel(const float* __restrict__ W,
                                                     unsigned short* __restrict__ Bp,
                                                     int K, int N, int T) {
    int idx = blockIdx.x * 256 + threadIdx.x;
    int NF = N >> 4;
    int total = T * NF * 64;
    if (idx >= total) return;
    int lane = idx & 63;
    int tnf = idx >> 6;
    int nf = tnf % NF;
    int t = tnf / NF;
    int kbase = t * 32 + (lane >> 4) * 8;
    int n = nf * 16 + (lane & 15);
    unsigned short v[8];
#pragma unroll
    for (int j = 0; j < 8; j++) {
        int k = kbase + j;
        float f = (k < K) ? W[(size_t)k * N + n] : 0.f;
        v[j] = f32_to_bf16(f);
    }
    uint4 p;
    p.x = (unsigned)v[0] | ((unsigned)v[1] << 16);
    p.y = (unsigned)v[2] | ((unsigned)v[3] << 16);
    p.z = (unsigned)v[4] | ((unsigned)v[5] << 16);
    p.w = (unsigned)v[6] | ((unsigned)v[7] << 16);
    *(uint4*)(Bp + (size_t)idx * 8) = p;
}

// ---------------------------------------------------------------------------
// LDS-free MFMA GEMM: C_bf16[M x NB] = A[M x K] * Bp. 256 thr = 4 waves, each
// wave computes 32 rows x NB cols (2 m-frags x NF n-frags of 16x16x32 MFMA).
// A loaded straight to fragments (each A row belongs to exactly one block);
// fp32 A converted in-register. No LDS, no barriers.
// ---------------------------------------------------------------------------
template <int NB, int K, bool ABF16>
__global__ __launch_bounds__(256) void gemm_mfma(const void* __restrict__ Avoid,
                                                 const unsigned short* __restrict__ Bp,
                                                 unsigned short* __restrict__ C, int M) {
    constexpr int NF = NB / 16;
    constexpr int FULL = K / 32;
    constexpr int REM = K % 32;
    const int lane = threadIdx.x & 63;
    const int wave = threadIdx.x >> 6;
    const int quad = lane >> 4;
    const int mrow = lane & 15;
    const int m_base = blockIdx.x * 128 + wave * 32;

    f32x4 acc[2][NF];
#pragma unroll
    for (int i = 0; i < 2; i++)
#pragma unroll
        for (int j = 0; j < NF; j++) acc[i][j] = (f32x4)(0.f);

    const int c0 = min(m_base + mrow, M - 1);        // clamped (stores guarded)
    const int c1 = min(m_base + 16 + mrow, M - 1);

    const float* Af = (const float*)Avoid;
    const unsigned short* Ah = (const unsigned short*)Avoid;

    for (int t = 0; t < FULL; t++) {
        const int k0 = t * 32 + quad * 8;
        bf16x8 a[2];
        if (ABF16) {
            a[0] = *(const bf16x8*)(Ah + (size_t)c0 * K + k0);
            a[1] = *(const bf16x8*)(Ah + (size_t)c1 * K + k0);
        } else {
            const float* p0 = Af + (size_t)c0 * K + k0;
            const float* p1 = Af + (size_t)c1 * K + k0;
            float4 x0 = *(const float4*)p0, y0 = *(const float4*)(p0 + 4);
            float4 x1 = *(const float4*)p1, y1 = *(const float4*)(p1 + 4);
            a[0][0] = (short)f32_to_bf16(x0.x); a[0][1] = (short)f32_to_bf16(x0.y);
            a[0][2] = (short)f32_to_bf16(x0.z); a[0][3] = (short)f32_to_bf16(x0.w);
            a[0][4] = (short)f32_to_bf16(y0.x); a[0][5] = (short)f32_to_bf16(y0.y);
            a[0][6] = (short)f32_to_bf16(y0.z); a[0][7] = (short)f32_to_bf16(y0.w);
            a[1][0] = (short)f32_to_bf16(x1.x); a[1][1] = (short)f32_to_bf16(x1.y);
            a[1][2] = (short)f32_to_bf16(x1.z); a[1][3] = (short)f32_to_bf16(x1.w);
            a[1][4] = (short)f32_to_bf16(y1.x); a[1][5] = (short)f32_to_bf16(y1.y);
            a[1][6] = (short)f32_to_bf16(y1.z); a[1][7] = (short)f32_to_bf16(y1.w);
        }
#pragma unroll
        for (int nf = 0; nf < NF; nf++) {
            bf16x8 b = *(const bf16x8*)(Bp + (size_t)(t * NF + nf) * 512 + lane * 8);
            acc[0][nf] = __builtin_amdgcn_mfma_f32_16x16x32_bf16(a[0], b, acc[0][nf], 0, 0, 0);
            acc[1][nf] = __builtin_amdgcn_mfma_f32_16x16x32_bf16(a[1], b, acc[1][nf], 0, 0, 0);
        }
    }
    if constexpr (REM > 0) {  // K tail: guarded element loads, B tile is zero-padded
        const int kb = FULL * 32 + quad * 8;
        bf16x8 a[2];
#pragma unroll
        for (int j = 0; j < 8; j++) {
            int k = kb + j;
            float v0 = 0.f, v1 = 0.f;
            if (k < K) {
                if (ABF16) {
                    v0 = bf16_to_f32(Ah[(size_t)c0 * K + k]);
                    v1 = bf16_to_f32(Ah[(size_t)c1 * K + k]);
                } else {
                    v0 = Af[(size_t)c0 * K + k];
                    v1 = Af[(size_t)c1 * K + k];
                }
            }
            a[0][j] = (short)f32_to_bf16(v0);
            a[1][j] = (short)f32_to_bf16(v1);
        }
#pragma unroll
        for (int nf = 0; nf < NF; nf++) {
            bf16x8 b = *(const bf16x8*)(Bp + (size_t)(FULL * NF + nf) * 512 + lane * 8);
            acc[0][nf] = __builtin_amdgcn_mfma_f32_16x16x32_bf16(a[0], b, acc[0][nf], 0, 0, 0);
            acc[1][nf] = __builtin_amdgcn_mfma_f32_16x16x32_bf16(a[1], b, acc[1][nf], 0, 0, 0);
        }
    }

    // epilogue: D[r][c], c = nf*16 + (lane&15), r = mf*16 + quad*4 + i
#pragma unroll
    for (int mf = 0; mf < 2; mf++)
#pragma unroll
        for (int i = 0; i < 4; i++) {
            const int r = m_base + mf * 16 + quad * 4 + i;
            if (r < M) {
#pragma unroll
                for (int nf = 0; nf < NF; nf++)
                    C[(size_t)r * NB + nf * 16 + mrow] = f32_to_bf16(acc[mf][nf][i]);
            }
        }
}

// ---------------------------------------------------------------------------
// Aggregation, bf16 h: out[i] = relu( sum dis_i*dis_s*h[s] + dis_i^2*h[i] + bias )
// One wave per node.
// ---------------------------------------------------------------------------
__global__ __launch_bounds__(256) void aggregate128_bf16(const unsigned int* __restrict__ h,
                                                         const float* __restrict__ dis,
                                                         const int* __restrict__ row_ptr,
                                                         const int* __restrict__ col,
                                                         const float* __restrict__ bias,
                                                         unsigned int* __restrict__ out, int n) {
    const int node = blockIdx.x * 4 + (threadIdx.x >> 6);
    const int lane = threadIdx.x & 63;
    if (node >= n) return;
    const float di = dis[node];
    const int beg = row_ptr[node], end = row_ptr[node + 1];
    unsigned v = h[(size_t)node * 64 + lane];
    const float wself = di * di;
    float ax = wself * __builtin_bit_cast(float, v << 16);
    float ay = wself * __builtin_bit_cast(float, v & 0xFFFF0000u);
    for (int j = beg; j < end; j++) {
        int s = col[j];
        float w = di * dis[s];
        unsigned u = h[(size_t)s * 64 + lane];
        ax = fmaf(w, __builtin_bit_cast(float, u << 16), ax);
        ay = fmaf(w, __builtin_bit_cast(float, u & 0xFFFF0000u), ay);
    }
    ax = fmaxf(ax + bias[2 * lane], 0.f);
    ay = fmaxf(ay + bias[2 * lane + 1], 0.f);
    out[(size_t)node * 64 + lane] = (unsigned)f32_to_bf16(ax) | ((unsigned)f32_to_bf16(ay) << 16);
}

__global__ __launch_bounds__(256) void aggregate64_bf16(const unsigned short* __restrict__ h,
                                                        const float* __restrict__ dis,
                                                        const int* __restrict__ row_ptr,
                                                        const int* __restrict__ col,
                                                        const float* __restrict__ bias,
                                                        float* __restrict__ out, int n) {
    const int node = blockIdx.x * 4 + (threadIdx.x >> 6);
    const int lane = threadIdx.x & 63;
    if (node >= n) return;
    const float di = dis[node];
    const int beg = row_ptr[node], end = row_ptr[node + 1];
    float acc = di * di * bf16_to_f32(h[(size_t)node * 64 + lane]);
    for (int j = beg; j < end; j++) {
        int s = col[j];
        acc = fmaf(di * dis[s], bf16_to_f32(h[(size_t)s * 64 + lane]), acc);
    }
    out[(size_t)node * 64 + lane] = fmaxf(acc + bias[lane], 0.f);
}

// ---------------------------------------------------------------------------
// classifier: out[M x 10] = A[M x 64] * Wc[64 x 10] + bc. 16 threads/row.
// ---------------------------------------------------------------------------
__global__ __launch_bounds__(256) void classifier_kernel(const float* __restrict__ A,
                                                         const float* __restrict__ Wc,
                                                         const float* __restrict__ bc,
                                                         float* __restrict__ out, int M) {
    int idx = blockIdx.x * 256 + threadIdx.x;
    int row = idx >> 4;
    int c = idx & 15;
    if (row >= M || c >= CDIM) return;
    const float* a = A + (size_t)row * H2DIM;
    float acc = bc[c];
#pragma unroll 8
    for (int k = 0; k < H2DIM; k++) acc = fmaf(a[k], Wc[k * CDIM + c], acc);
    out[(size_t)row * CDIM + c] = acc;
}

// ---------------------------------------------------------------------------

extern "C" void kernel_launch(void* const* d_in, const int* in_sizes, int n_in,
                              void* d_out, int out_size, void* d_ws, size_t ws_size,
                              hipStream_t stream) {
    const float* x  = (const float*)d_in[0];
    const int*   ei = (const int*)d_in[1];
    const float* W1 = (const float*)d_in[2];
    const float* b1 = (const float*)d_in[3];
    const float* W2 = (const float*)d_in[4];
    const float* b2 = (const float*)d_in[5];
    const float* Wc = (const float*)d_in[6];
    const float* bc = (const float*)d_in[7];
    float* out = (float*)d_out;

    const int N = in_sizes[0] / FDIM;  // 100000
    const int E = in_sizes[1] / 2;     // 1600000
    const int* src = ei;
    const int* dst = ei + E;

    // workspace layout (bytes)
    char* ws = (char*)d_ws;
    int*            cnt    = (int*)(ws + 0x000000);   // N ints (reused as cursor)
    int*            rowptr = (int*)(ws + 0x080000);   // N+1 ints
    float*          dis    = (float*)(ws + 0x100000); // N floats
    int*            bsums  = (int*)(ws + 0x180000);   // ceil(N/256) ints
    int*            col    = (int*)(ws + 0x200000);   // E ints (6.4 MB)
    unsigned short* W1p    = (unsigned short*)(ws + 0x880000);  // 16*8*64*8 bf16 = 128 KB
    unsigned short* W2p    = (unsigned short*)(ws + 0x8C0000);  // 4*4*64*8 bf16 = 16 KB
    unsigned short* h1     = (unsigned short*)(ws + 0x900000);  // M*128 bf16 (25.6 MB)
    unsigned short* agg1   = (unsigned short*)(ws + 0x2200000); // M*128 bf16 (25.6 MB)
    unsigned short* h2     = (unsigned short*)(ws + 0x3B00000); // M*64 bf16 (12.8 MB)
    float*          agg2f  = (float*)(ws + 0x4800000);          // M*64 fp32 (25.6 MB)

    const int nb = (N + 255) / 256;

    // 1. CSR build + dis (independent of GEMM1)
    hipMemsetAsync(cnt, 0, (size_t)N * sizeof(int), stream);
    hist_kernel<<<(E + 255) / 256, 256, 0, stream>>>(dst, cnt, E);
    dis_kernel<<<nb, 256, 0, stream>>>(cnt, dis, N);
    block_reduce_kernel<<<nb, 256, 0, stream>>>(cnt, bsums, N);
    scan_sums_kernel<<<1, 512, 0, stream>>>(bsums, nb, rowptr, N);
    scan_blocks_kernel<<<nb, 256, 0, stream>>>(cnt, bsums, rowptr, /*cursor=*/cnt, N);
    fill_kernel<<<(E + 255) / 256, 256, 0, stream>>>(src, dst, /*cursor=*/cnt, col, E);

    // 2. pack weights to MFMA B-fragment bf16 layout
    pack_w_kernel<<<(16 * 8 * 64 + 255) / 256, 256, 0, stream>>>(W1, W1p, FDIM, H1DIM, 16);
    pack_w_kernel<<<(4 * 4 * 64 + 255) / 256, 256, 0, stream>>>(W2, W2p, H1DIM, H2DIM, 4);

    const int gblocks = (N + 127) / 128;  // 782

    // 3. layer 1
    gemm_mfma<H1DIM, FDIM, false><<<gblocks, 256, 0, stream>>>(x, W1p, h1, N);
    aggregate128_bf16<<<(N + 3) / 4, 256, 0, stream>>>((const unsigned int*)h1, dis, rowptr,
                                                       col, b1, (unsigned int*)agg1, N);
    // 4. layer 2
    gemm_mfma<H2DIM, H1DIM, true><<<gblocks, 256, 0, stream>>>(agg1, W2p, h2, N);
    aggregate64_bf16<<<(N + 3) / 4, 256, 0, stream>>>(h2, dis, rowptr, col, b2, agg2f, N);

    // 5. classifier
    classifier_kernel<<<(N * 16 + 255) / 256, 256, 0, stream>>>(agg2f, Wc, bc, out, N);
}

// Round 4
// 633.059 us; speedup vs baseline: 2.8861x; 1.4376x over previous
//
#include <hip/hip_runtime.h>

// Problem constants (from reference setup_inputs)
#define FDIM 500
#define H1DIM 128
#define H2DIM 64
#define CDIM 10

using f32x4 = __attribute__((ext_vector_type(4))) float;
using bf16x8 = __attribute__((ext_vector_type(8))) short;  // 8 bf16 in 4 VGPRs

__device__ __forceinline__ unsigned short f32_to_bf16(float f) {
    unsigned u = __builtin_bit_cast(unsigned, f);
    u += 0x7FFFu + ((u >> 16) & 1u);  // RNE (inputs are finite, no NaN handling)
    return (unsigned short)(u >> 16);
}
__device__ __forceinline__ float bf16_to_f32(unsigned short h) {
    return __builtin_bit_cast(float, (unsigned)h << 16);
}
__device__ __forceinline__ float blo(unsigned u) {
    return __builtin_bit_cast(float, u << 16);
}
__device__ __forceinline__ float bhi(unsigned u) {
    return __builtin_bit_cast(float, u & 0xFFFF0000u);
}

// ---------------------------------------------------------------------------
// CSR build: histogram -> two-level scan -> atomic-cursor fill. dis = rsqrt(deg+1).
// fill also precomputes per-edge weight: ew[pos] = {src, dis[src]*dis[dst]}.
// ---------------------------------------------------------------------------

__global__ __launch_bounds__(256) void hist_kernel(const int* __restrict__ dst,
                                                   int* __restrict__ cnt, int E) {
    int e = blockIdx.x * 256 + threadIdx.x;
    if (e < E) atomicAdd(&cnt[dst[e]], 1);
}

__global__ __launch_bounds__(256) void dis_kernel(const int* __restrict__ cnt,
                                                  float* __restrict__ dis, int n) {
    int i = blockIdx.x * 256 + threadIdx.x;
    if (i < n) dis[i] = rsqrtf((float)cnt[i] + 1.0f);  // +1 self loop
}

__global__ __launch_bounds__(256) void block_reduce_kernel(const int* __restrict__ cnt,
                                                           int* __restrict__ bsums, int n) {
    __shared__ int s[256];
    int i = blockIdx.x * 256 + threadIdx.x;
    s[threadIdx.x] = (i < n) ? cnt[i] : 0;
    __syncthreads();
    for (int o = 128; o > 0; o >>= 1) {
        if (threadIdx.x < o) s[threadIdx.x] += s[threadIdx.x + o];
        __syncthreads();
    }
    if (threadIdx.x == 0) bsums[blockIdx.x] = s[0];
}

__global__ __launch_bounds__(512) void scan_sums_kernel(int* __restrict__ bsums, int nb,
                                                        int* __restrict__ row_ptr, int n) {
    __shared__ int s[512];
    int v = (threadIdx.x < nb) ? bsums[threadIdx.x] : 0;
    s[threadIdx.x] = v;
    __syncthreads();
    for (int o = 1; o < 512; o <<= 1) {
        int t = (threadIdx.x >= o) ? s[threadIdx.x - o] : 0;
        __syncthreads();
        s[threadIdx.x] += t;
        __syncthreads();
    }
    if (threadIdx.x < nb) bsums[threadIdx.x] = s[threadIdx.x] - v;  // exclusive
    if (threadIdx.x == 511) row_ptr[n] = s[511];                    // total == E
}

__global__ __launch_bounds__(256) void scan_blocks_kernel(const int* __restrict__ cnt,
                                                          const int* __restrict__ bsums,
                                                          int* __restrict__ row_ptr,
                                                          int* __restrict__ cursor, int n) {
    __shared__ int s[256];
    int i = blockIdx.x * 256 + threadIdx.x;
    int v = (i < n) ? cnt[i] : 0;
    s[threadIdx.x] = v;
    __syncthreads();
    for (int o = 1; o < 256; o <<= 1) {
        int t = (threadIdx.x >= o) ? s[threadIdx.x - o] : 0;
        __syncthreads();
        s[threadIdx.x] += t;
        __syncthreads();
    }
    int excl = s[threadIdx.x] - v + bsums[blockIdx.x];
    if (i < n) {
        row_ptr[i] = excl;
        cursor[i] = excl;
    }
}

__global__ __launch_bounds__(256) void fill_kernel(const int* __restrict__ src,
                                                   const int* __restrict__ dst,
                                                   const float* __restrict__ dis,
                                                   int* __restrict__ cursor,
                                                   int2* __restrict__ ew, int E) {
    int e = blockIdx.x * 256 + threadIdx.x;
    if (e < E) {
        int d = dst[e];
        int s = src[e];
        int pos = atomicAdd(&cursor[d], 1);
        float w = dis[s] * dis[d];
        ew[pos] = make_int2(s, __builtin_bit_cast(int, w));
    }
}

// ---------------------------------------------------------------------------
// Pre-pack W (fp32 [K,N]) into MFMA B-fragment layout, bf16, K zero-padded.
// ---------------------------------------------------------------------------
__global__ __launch_bounds__(256) void pack_w_kernel(const float* __restrict__ W,
                                                     unsigned short* __restrict__ Bp,
                                                     int K, int N, int T) {
    int idx = blockIdx.x * 256 + threadIdx.x;
    int NF = N >> 4;
    int total = T * NF * 64;
    if (idx >= total) return;
    int lane = idx & 63;
    int tnf = idx >> 6;
    int nf = tnf % NF;
    int t = tnf / NF;
    int kbase = t * 32 + (lane >> 4) * 8;
    int n = nf * 16 + (lane & 15);
    unsigned short v[8];
#pragma unroll
    for (int j = 0; j < 8; j++) {
        int k = kbase + j;
        float f = (k < K) ? W[(size_t)k * N + n] : 0.f;
        v[j] = f32_to_bf16(f);
    }
    uint4 p;
    p.x = (unsigned)v[0] | ((unsigned)v[1] << 16);
    p.y = (unsigned)v[2] | ((unsigned)v[3] << 16);
    p.z = (unsigned)v[4] | ((unsigned)v[5] << 16);
    p.w = (unsigned)v[6] | ((unsigned)v[7] << 16);
    *(uint4*)(Bp + (size_t)idx * 8) = p;
}

// ---------------------------------------------------------------------------
// LDS-free MFMA GEMM: C_bf16[M x NB] = A[M x K] * Bp. 4 waves x 32 rows.
// ---------------------------------------------------------------------------
template <int NB, int K, bool ABF16>
__global__ __launch_bounds__(256) void gemm_mfma(const void* __restrict__ Avoid,
                                                 const unsigned short* __restrict__ Bp,
                                                 unsigned short* __restrict__ C, int M) {
    constexpr int NF = NB / 16;
    constexpr int FULL = K / 32;
    constexpr int REM = K % 32;
    const int lane = threadIdx.x & 63;
    const int wave = threadIdx.x >> 6;
    const int quad = lane >> 4;
    const int mrow = lane & 15;
    const int m_base = blockIdx.x * 128 + wave * 32;

    f32x4 acc[2][NF];
#pragma unroll
    for (int i = 0; i < 2; i++)
#pragma unroll
        for (int j = 0; j < NF; j++) acc[i][j] = (f32x4)(0.f);

    const int c0 = min(m_base + mrow, M - 1);  // clamped (stores guarded)
    const int c1 = min(m_base + 16 + mrow, M - 1);

    const float* Af = (const float*)Avoid;
    const unsigned short* Ah = (const unsigned short*)Avoid;

    for (int t = 0; t < FULL; t++) {
        const int k0 = t * 32 + quad * 8;
        bf16x8 a[2];
        if (ABF16) {
            a[0] = *(const bf16x8*)(Ah + (size_t)c0 * K + k0);
            a[1] = *(const bf16x8*)(Ah + (size_t)c1 * K + k0);
        } else {
            const float* p0 = Af + (size_t)c0 * K + k0;
            const float* p1 = Af + (size_t)c1 * K + k0;
            float4 x0 = *(const float4*)p0, y0 = *(const float4*)(p0 + 4);
            float4 x1 = *(const float4*)p1, y1 = *(const float4*)(p1 + 4);
            a[0][0] = (short)f32_to_bf16(x0.x); a[0][1] = (short)f32_to_bf16(x0.y);
            a[0][2] = (short)f32_to_bf16(x0.z); a[0][3] = (short)f32_to_bf16(x0.w);
            a[0][4] = (short)f32_to_bf16(y0.x); a[0][5] = (short)f32_to_bf16(y0.y);
            a[0][6] = (short)f32_to_bf16(y0.z); a[0][7] = (short)f32_to_bf16(y0.w);
            a[1][0] = (short)f32_to_bf16(x1.x); a[1][1] = (short)f32_to_bf16(x1.y);
            a[1][2] = (short)f32_to_bf16(x1.z); a[1][3] = (short)f32_to_bf16(x1.w);
            a[1][4] = (short)f32_to_bf16(y1.x); a[1][5] = (short)f32_to_bf16(y1.y);
            a[1][6] = (short)f32_to_bf16(y1.z); a[1][7] = (short)f32_to_bf16(y1.w);
        }
#pragma unroll
        for (int nf = 0; nf < NF; nf++) {
            bf16x8 b = *(const bf16x8*)(Bp + (size_t)(t * NF + nf) * 512 + lane * 8);
            acc[0][nf] = __builtin_amdgcn_mfma_f32_16x16x32_bf16(a[0], b, acc[0][nf], 0, 0, 0);
            acc[1][nf] = __builtin_amdgcn_mfma_f32_16x16x32_bf16(a[1], b, acc[1][nf], 0, 0, 0);
        }
    }
    if constexpr (REM > 0) {  // K tail: guarded element loads, B tile zero-padded
        const int kb = FULL * 32 + quad * 8;
        bf16x8 a[2];
#pragma unroll
        for (int j = 0; j < 8; j++) {
            int k = kb + j;
            float v0 = 0.f, v1 = 0.f;
            if (k < K) {
                if (ABF16) {
                    v0 = bf16_to_f32(Ah[(size_t)c0 * K + k]);
                    v1 = bf16_to_f32(Ah[(size_t)c1 * K + k]);
                } else {
                    v0 = Af[(size_t)c0 * K + k];
                    v1 = Af[(size_t)c1 * K + k];
                }
            }
            a[0][j] = (short)f32_to_bf16(v0);
            a[1][j] = (short)f32_to_bf16(v1);
        }
#pragma unroll
        for (int nf = 0; nf < NF; nf++) {
            bf16x8 b = *(const bf16x8*)(Bp + (size_t)(FULL * NF + nf) * 512 + lane * 8);
            acc[0][nf] = __builtin_amdgcn_mfma_f32_16x16x32_bf16(a[0], b, acc[0][nf], 0, 0, 0);
            acc[1][nf] = __builtin_amdgcn_mfma_f32_16x16x32_bf16(a[1], b, acc[1][nf], 0, 0, 0);
        }
    }

#pragma unroll
    for (int mf = 0; mf < 2; mf++)
#pragma unroll
        for (int i = 0; i < 4; i++) {
            const int r = m_base + mf * 16 + quad * 4 + i;
            if (r < M) {
#pragma unroll
                for (int nf = 0; nf < NF; nf++)
                    C[(size_t)r * NB + nf * 16 + mrow] = f32_to_bf16(acc[mf][nf][i]);
            }
        }
}

// ---------------------------------------------------------------------------
// Aggregation v2 (D=128, bf16->bf16): one wave/node, half-wave per edge,
// uint2 (4 bf16)/lane, 2 edges/step x unroll 4 = 8 gathers in flight.
// out[i] = relu( sum_e w_e * h[src_e] + di^2 * h[i] + bias )
// ---------------------------------------------------------------------------
__global__ __launch_bounds__(256) void aggregate128_v2(const uint2* __restrict__ h,
                                                       const float* __restrict__ dis,
                                                       const int* __restrict__ row_ptr,
                                                       const int2* __restrict__ ew,
                                                       const float* __restrict__ bias,
                                                       uint2* __restrict__ out, int n) {
    const int node = blockIdx.x * 4 + (threadIdx.x >> 6);
    if (node >= n) return;
    const int lane = threadIdx.x & 63;
    const int half = lane >> 5;
    const int c = lane & 31;  // uint2 index in row; channels 4c..4c+3
    const float di = dis[node];
    const int beg = row_ptr[node], end = row_ptr[node + 1];

    float ax0, ax1, ax2, ax3;
    {
        uint2 v = h[(size_t)node * 32 + c];
        float ws = half ? 0.f : di * di;  // self term counted once
        ax0 = ws * blo(v.x); ax1 = ws * bhi(v.x);
        ax2 = ws * blo(v.y); ax3 = ws * bhi(v.y);
    }
    for (int jb = beg; jb < end; jb += 8) {
        const int e0 = jb + half, e1 = e0 + 2, e2 = e0 + 4, e3 = e0 + 6;
        int2 p0 = ew[min(e0, end - 1)];
        int2 p1 = ew[min(e1, end - 1)];
        int2 p2 = ew[min(e2, end - 1)];
        int2 p3 = ew[min(e3, end - 1)];
        float w0 = (e0 < end) ? __builtin_bit_cast(float, p0.y) : 0.f;
        float w1 = (e1 < end) ? __builtin_bit_cast(float, p1.y) : 0.f;
        float w2 = (e2 < end) ? __builtin_bit_cast(float, p2.y) : 0.f;
        float w3 = (e3 < end) ? __builtin_bit_cast(float, p3.y) : 0.f;
        uint2 v0 = h[(size_t)p0.x * 32 + c];
        uint2 v1 = h[(size_t)p1.x * 32 + c];
        uint2 v2 = h[(size_t)p2.x * 32 + c];
        uint2 v3 = h[(size_t)p3.x * 32 + c];
        ax0 = fmaf(w0, blo(v0.x), ax0); ax1 = fmaf(w0, bhi(v0.x), ax1);
        ax2 = fmaf(w0, blo(v0.y), ax2); ax3 = fmaf(w0, bhi(v0.y), ax3);
        ax0 = fmaf(w1, blo(v1.x), ax0); ax1 = fmaf(w1, bhi(v1.x), ax1);
        ax2 = fmaf(w1, blo(v1.y), ax2); ax3 = fmaf(w1, bhi(v1.y), ax3);
        ax0 = fmaf(w2, blo(v2.x), ax0); ax1 = fmaf(w2, bhi(v2.x), ax1);
        ax2 = fmaf(w2, blo(v2.y), ax2); ax3 = fmaf(w2, bhi(v2.y), ax3);
        ax0 = fmaf(w3, blo(v3.x), ax0); ax1 = fmaf(w3, bhi(v3.x), ax1);
        ax2 = fmaf(w3, blo(v3.y), ax2); ax3 = fmaf(w3, bhi(v3.y), ax3);
    }
    ax0 += __shfl_xor(ax0, 32);
    ax1 += __shfl_xor(ax1, 32);
    ax2 += __shfl_xor(ax2, 32);
    ax3 += __shfl_xor(ax3, 32);
    if (half == 0) {
        const float4 b = *(const float4*)(bias + 4 * c);
        uint2 r;
        r.x = (unsigned)f32_to_bf16(fmaxf(ax0 + b.x, 0.f)) |
              ((unsigned)f32_to_bf16(fmaxf(ax1 + b.y, 0.f)) << 16);
        r.y = (unsigned)f32_to_bf16(fmaxf(ax2 + b.z, 0.f)) |
              ((unsigned)f32_to_bf16(fmaxf(ax3 + b.w, 0.f)) << 16);
        out[(size_t)node * 32 + c] = r;
    }
}

// ---------------------------------------------------------------------------
// Aggregation v2 (D=64, bf16->fp32): one wave/node, quad per edge,
// uint2 (4 bf16)/lane, 4 edges/step x unroll 2 = 8 gathers in flight.
// ---------------------------------------------------------------------------
__global__ __launch_bounds__(256) void aggregate64_v2(const uint2* __restrict__ h,
                                                      const float* __restrict__ dis,
                                                      const int* __restrict__ row_ptr,
                                                      const int2* __restrict__ ew,
                                                      const float* __restrict__ bias,
                                                      float4* __restrict__ out, int n) {
    const int node = blockIdx.x * 4 + (threadIdx.x >> 6);
    if (node >= n) return;
    const int lane = threadIdx.x & 63;
    const int quad = lane >> 4;
    const int c = lane & 15;  // uint2 index in row; channels 4c..4c+3
    const float di = dis[node];
    const int beg = row_ptr[node], end = row_ptr[node + 1];

    float ax0, ax1, ax2, ax3;
    {
        uint2 v = h[(size_t)node * 16 + c];
        float ws = quad ? 0.f : di * di;
        ax0 = ws * blo(v.x); ax1 = ws * bhi(v.x);
        ax2 = ws * blo(v.y); ax3 = ws * bhi(v.y);
    }
    for (int jb = beg; jb < end; jb += 8) {
        const int e0 = jb + quad, e1 = e0 + 4;
        int2 p0 = ew[min(e0, end - 1)];
        int2 p1 = ew[min(e1, end - 1)];
        float w0 = (e0 < end) ? __builtin_bit_cast(float, p0.y) : 0.f;
        float w1 = (e1 < end) ? __builtin_bit_cast(float, p1.y) : 0.f;
        uint2 v0 = h[(size_t)p0.x * 16 + c];
        uint2 v1 = h[(size_t)p1.x * 16 + c];
        ax0 = fmaf(w0, blo(v0.x), ax0); ax1 = fmaf(w0, bhi(v0.x), ax1);
        ax2 = fmaf(w0, blo(v0.y), ax2); ax3 = fmaf(w0, bhi(v0.y), ax3);
        ax0 = fmaf(w1, blo(v1.x), ax0); ax1 = fmaf(w1, bhi(v1.x), ax1);
        ax2 = fmaf(w1, blo(v1.y), ax2); ax3 = fmaf(w1, bhi(v1.y), ax3);
    }
    ax0 += __shfl_xor(ax0, 16); ax0 += __shfl_xor(ax0, 32);
    ax1 += __shfl_xor(ax1, 16); ax1 += __shfl_xor(ax1, 32);
    ax2 += __shfl_xor(ax2, 16); ax2 += __shfl_xor(ax2, 32);
    ax3 += __shfl_xor(ax3, 16); ax3 += __shfl_xor(ax3, 32);
    if (lane < 16) {
        const float4 b = *(const float4*)(bias + 4 * c);
        float4 r;
        r.x = fmaxf(ax0 + b.x, 0.f);
        r.y = fmaxf(ax1 + b.y, 0.f);
        r.z = fmaxf(ax2 + b.z, 0.f);
        r.w = fmaxf(ax3 + b.w, 0.f);
        out[(size_t)node * 16 + c] = r;
    }
}

// ---------------------------------------------------------------------------
// classifier: out[M x 10] = A[M x 64] * Wc[64 x 10] + bc. 16 threads/row.
// ---------------------------------------------------------------------------
__global__ __launch_bounds__(256) void classifier_kernel(const float* __restrict__ A,
                                                         const float* __restrict__ Wc,
                                                         const float* __restrict__ bc,
                                                         float* __restrict__ out, int M) {
    int idx = blockIdx.x * 256 + threadIdx.x;
    int row = idx >> 4;
    int c = idx & 15;
    if (row >= M || c >= CDIM) return;
    const float* a = A + (size_t)row * H2DIM;
    float acc = bc[c];
#pragma unroll 8
    for (int k = 0; k < H2DIM; k++) acc = fmaf(a[k], Wc[k * CDIM + c], acc);
    out[(size_t)row * CDIM + c] = acc;
}

// ---------------------------------------------------------------------------

extern "C" void kernel_launch(void* const* d_in, const int* in_sizes, int n_in,
                              void* d_out, int out_size, void* d_ws, size_t ws_size,
                              hipStream_t stream) {
    const float* x  = (const float*)d_in[0];
    const int*   ei = (const int*)d_in[1];
    const float* W1 = (const float*)d_in[2];
    const float* b1 = (const float*)d_in[3];
    const float* W2 = (const float*)d_in[4];
    const float* b2 = (const float*)d_in[5];
    const float* Wc = (const float*)d_in[6];
    const float* bc = (const float*)d_in[7];
    float* out = (float*)d_out;

    const int N = in_sizes[0] / FDIM;  // 100000
    const int E = in_sizes[1] / 2;     // 1600000
    const int* src = ei;
    const int* dst = ei + E;

    // workspace layout (bytes); agg2f overlays h1 (h1 dead after aggregate128)
    char* ws = (char*)d_ws;
    int*            cnt    = (int*)(ws + 0x000000);   // N ints (reused as cursor)
    int*            rowptr = (int*)(ws + 0x080000);   // N+1 ints
    float*          dis    = (float*)(ws + 0x100000); // N floats
    int*            bsums  = (int*)(ws + 0x180000);   // ceil(N/256) ints
    int2*           ew     = (int2*)(ws + 0x200000);  // E int2 (12.8 MB)
    unsigned short* W1p    = (unsigned short*)(ws + 0xE40000);  // 128 KB
    unsigned short* W2p    = (unsigned short*)(ws + 0xE80000);  // 16 KB
    unsigned short* h1     = (unsigned short*)(ws + 0xF00000);  // N*128 bf16 (25.6 MB)
    float*          agg2f  = (float*)(ws + 0xF00000);           // N*64 fp32 (overlays h1)
    unsigned short* agg1   = (unsigned short*)(ws + 0x2800000); // N*128 bf16 (25.6 MB)
    unsigned short* h2     = (unsigned short*)(ws + 0x4200000); // N*64 bf16 (12.8 MB)

    const int nb = (N + 255) / 256;

    // 1. CSR build + dis + per-edge weights
    hipMemsetAsync(cnt, 0, (size_t)N * sizeof(int), stream);
    hist_kernel<<<(E + 255) / 256, 256, 0, stream>>>(dst, cnt, E);
    dis_kernel<<<nb, 256, 0, stream>>>(cnt, dis, N);
    block_reduce_kernel<<<nb, 256, 0, stream>>>(cnt, bsums, N);
    scan_sums_kernel<<<1, 512, 0, stream>>>(bsums, nb, rowptr, N);
    scan_blocks_kernel<<<nb, 256, 0, stream>>>(cnt, bsums, rowptr, /*cursor=*/cnt, N);
    fill_kernel<<<(E + 255) / 256, 256, 0, stream>>>(src, dst, dis, /*cursor=*/cnt, ew, E);

    // 2. pack weights to MFMA B-fragment bf16 layout
    pack_w_kernel<<<(16 * 8 * 64 + 255) / 256, 256, 0, stream>>>(W1, W1p, FDIM, H1DIM, 16);
    pack_w_kernel<<<(4 * 4 * 64 + 255) / 256, 256, 0, stream>>>(W2, W2p, H1DIM, H2DIM, 4);

    const int gblocks = (N + 127) / 128;  // 782

    // 3. layer 1
    gemm_mfma<H1DIM, FDIM, false><<<gblocks, 256, 0, stream>>>(x, W1p, h1, N);
    aggregate128_v2<<<(N + 3) / 4, 256, 0, stream>>>((const uint2*)h1, dis, rowptr, ew, b1,
                                                     (uint2*)agg1, N);
    // 4. layer 2
    gemm_mfma<H2DIM, H1DIM, true><<<gblocks, 256, 0, stream>>>(agg1, W2p, h2, N);
    aggregate64_v2<<<(N + 3) / 4, 256, 0, stream>>>((const uint2*)h2, dis, rowptr, ew, b2,
                                                    (float4*)agg2f, N);

    // 5. classifier
    classifier_kernel<<<(N * 16 + 255) / 256, 256, 0, stream>>>(agg2f, Wc, bc, out, N);
}

// Round 5
// 628.175 us; speedup vs baseline: 2.9085x; 1.0078x over previous
//
#include <hip/hip_runtime.h>

// Problem constants (from reference setup_inputs)
#define FDIM 500
#define H1DIM 128
#define H2DIM 64
#define CDIM 10

using f32x4 = __attribute__((ext_vector_type(4))) float;
using bf16x8 = __attribute__((ext_vector_type(8))) short;  // 8 bf16 in 4 VGPRs

__device__ __forceinline__ unsigned short f32_to_bf16(float f) {
    unsigned u = __builtin_bit_cast(unsigned, f);
    u += 0x7FFFu + ((u >> 16) & 1u);  // RNE (inputs are finite, no NaN handling)
    return (unsigned short)(u >> 16);
}
__device__ __forceinline__ float bf16_to_f32(unsigned short h) {
    return __builtin_bit_cast(float, (unsigned)h << 16);
}
__device__ __forceinline__ float blo(unsigned u) {
    return __builtin_bit_cast(float, u << 16);
}
__device__ __forceinline__ float bhi(unsigned u) {
    return __builtin_bit_cast(float, u & 0xFFFF0000u);
}

// ---------------------------------------------------------------------------
// CSR build: histogram -> two-level scan -> atomic-cursor fill. dis = rsqrt(deg+1).
// fill also precomputes per-edge weight: ew[pos] = {src, dis[src]*dis[dst]}.
// ---------------------------------------------------------------------------

__global__ __launch_bounds__(256) void hist_kernel(const int* __restrict__ dst,
                                                   int* __restrict__ cnt, int E) {
    int e = blockIdx.x * 256 + threadIdx.x;
    if (e < E) atomicAdd(&cnt[dst[e]], 1);
}

__global__ __launch_bounds__(256) void dis_kernel(const int* __restrict__ cnt,
                                                  float* __restrict__ dis, int n) {
    int i = blockIdx.x * 256 + threadIdx.x;
    if (i < n) dis[i] = rsqrtf((float)cnt[i] + 1.0f);  // +1 self loop
}

__global__ __launch_bounds__(256) void block_reduce_kernel(const int* __restrict__ cnt,
                                                           int* __restrict__ bsums, int n) {
    __shared__ int s[256];
    int i = blockIdx.x * 256 + threadIdx.x;
    s[threadIdx.x] = (i < n) ? cnt[i] : 0;
    __syncthreads();
    for (int o = 128; o > 0; o >>= 1) {
        if (threadIdx.x < o) s[threadIdx.x] += s[threadIdx.x + o];
        __syncthreads();
    }
    if (threadIdx.x == 0) bsums[blockIdx.x] = s[0];
}

__global__ __launch_bounds__(512) void scan_sums_kernel(int* __restrict__ bsums, int nb,
                                                        int* __restrict__ row_ptr, int n) {
    __shared__ int s[512];
    int v = (threadIdx.x < nb) ? bsums[threadIdx.x] : 0;
    s[threadIdx.x] = v;
    __syncthreads();
    for (int o = 1; o < 512; o <<= 1) {
        int t = (threadIdx.x >= o) ? s[threadIdx.x - o] : 0;
        __syncthreads();
        s[threadIdx.x] += t;
        __syncthreads();
    }
    if (threadIdx.x < nb) bsums[threadIdx.x] = s[threadIdx.x] - v;  // exclusive
    if (threadIdx.x == 511) row_ptr[n] = s[511];                    // total == E
}

__global__ __launch_bounds__(256) void scan_blocks_kernel(const int* __restrict__ cnt,
                                                          const int* __restrict__ bsums,
                                                          int* __restrict__ row_ptr,
                                                          int* __restrict__ cursor, int n) {
    __shared__ int s[256];
    int i = blockIdx.x * 256 + threadIdx.x;
    int v = (i < n) ? cnt[i] : 0;
    s[threadIdx.x] = v;
    __syncthreads();
    for (int o = 1; o < 256; o <<= 1) {
        int t = (threadIdx.x >= o) ? s[threadIdx.x - o] : 0;
        __syncthreads();
        s[threadIdx.x] += t;
        __syncthreads();
    }
    int excl = s[threadIdx.x] - v + bsums[blockIdx.x];
    if (i < n) {
        row_ptr[i] = excl;
        cursor[i] = excl;
    }
}

__global__ __launch_bounds__(256) void fill_kernel(const int* __restrict__ src,
                                                   const int* __restrict__ dst,
                                                   const float* __restrict__ dis,
                                                   int* __restrict__ cursor,
                                                   int2* __restrict__ ew, int E) {
    int e = blockIdx.x * 256 + threadIdx.x;
    if (e < E) {
        int d = dst[e];
        int s = src[e];
        int pos = atomicAdd(&cursor[d], 1);
        float w = dis[s] * dis[d];
        ew[pos] = make_int2(s, __builtin_bit_cast(int, w));
    }
}

// ---------------------------------------------------------------------------
// Pre-pack W (fp32 [K,N]) into MFMA B-fragment layout, bf16, K zero-padded.
// ---------------------------------------------------------------------------
__global__ __launch_bounds__(256) void pack_w_kernel(const float* __restrict__ W,
                                                     unsigned short* __restrict__ Bp,
                                                     int K, int N, int T) {
    int idx = blockIdx.x * 256 + threadIdx.x;
    int NF = N >> 4;
    int total = T * NF * 64;
    if (idx >= total) return;
    int lane = idx & 63;
    int tnf = idx >> 6;
    int nf = tnf % NF;
    int t = tnf / NF;
    int kbase = t * 32 + (lane >> 4) * 8;
    int n = nf * 16 + (lane & 15);
    unsigned short v[8];
#pragma unroll
    for (int j = 0; j < 8; j++) {
        int k = kbase + j;
        float f = (k < K) ? W[(size_t)k * N + n] : 0.f;
        v[j] = f32_to_bf16(f);
    }
    uint4 p;
    p.x = (unsigned)v[0] | ((unsigned)v[1] << 16);
    p.y = (unsigned)v[2] | ((unsigned)v[3] << 16);
    p.z = (unsigned)v[4] | ((unsigned)v[5] << 16);
    p.w = (unsigned)v[6] | ((unsigned)v[7] << 16);
    *(uint4*)(Bp + (size_t)idx * 8) = p;
}

// ---------------------------------------------------------------------------
// LDS-free MFMA GEMM v2: 64 rows per wave (4 m-frags) -> 2x register B-reuse
// vs 32-row version. One wave per 64-thread block; grid = ceil(M/64).
// ---------------------------------------------------------------------------
template <int NB, int K, bool ABF16>
__global__ __launch_bounds__(64) void gemm_mfma(const void* __restrict__ Avoid,
                                                const unsigned short* __restrict__ Bp,
                                                unsigned short* __restrict__ C, int M) {
    constexpr int NF = NB / 16;
    constexpr int FULL = K / 32;
    constexpr int REM = K % 32;
    const int lane = threadIdx.x;
    const int quad = lane >> 4;
    const int mrow = lane & 15;
    const int m_base = blockIdx.x * 64;

    f32x4 acc[4][NF];
#pragma unroll
    for (int i = 0; i < 4; i++)
#pragma unroll
        for (int j = 0; j < NF; j++) acc[i][j] = (f32x4)(0.f);

    int c[4];
#pragma unroll
    for (int i = 0; i < 4; i++) c[i] = min(m_base + i * 16 + mrow, M - 1);  // stores guarded

    const float* Af = (const float*)Avoid;
    const unsigned short* Ah = (const unsigned short*)Avoid;

    for (int t = 0; t < FULL; t++) {
        const int k0 = t * 32 + quad * 8;
        bf16x8 a[4];
        if (ABF16) {
#pragma unroll
            for (int i = 0; i < 4; i++)
                a[i] = *(const bf16x8*)(Ah + (size_t)c[i] * K + k0);
        } else {
#pragma unroll
            for (int i = 0; i < 4; i++) {
                const float* p = Af + (size_t)c[i] * K + k0;
                float4 x = *(const float4*)p, y = *(const float4*)(p + 4);
                a[i][0] = (short)f32_to_bf16(x.x); a[i][1] = (short)f32_to_bf16(x.y);
                a[i][2] = (short)f32_to_bf16(x.z); a[i][3] = (short)f32_to_bf16(x.w);
                a[i][4] = (short)f32_to_bf16(y.x); a[i][5] = (short)f32_to_bf16(y.y);
                a[i][6] = (short)f32_to_bf16(y.z); a[i][7] = (short)f32_to_bf16(y.w);
            }
        }
#pragma unroll
        for (int nf = 0; nf < NF; nf++) {
            bf16x8 b = *(const bf16x8*)(Bp + (size_t)(t * NF + nf) * 512 + lane * 8);
#pragma unroll
            for (int i = 0; i < 4; i++)
                acc[i][nf] = __builtin_amdgcn_mfma_f32_16x16x32_bf16(a[i], b, acc[i][nf], 0, 0, 0);
        }
    }
    if constexpr (REM > 0) {  // K tail: guarded element loads, B tile zero-padded
        const int kb = FULL * 32 + quad * 8;
        bf16x8 a[4];
#pragma unroll
        for (int i = 0; i < 4; i++) {
#pragma unroll
            for (int j = 0; j < 8; j++) {
                int k = kb + j;
                float v = 0.f;
                if (k < K)
                    v = ABF16 ? bf16_to_f32(Ah[(size_t)c[i] * K + k]) : Af[(size_t)c[i] * K + k];
                a[i][j] = (short)f32_to_bf16(v);
            }
        }
#pragma unroll
        for (int nf = 0; nf < NF; nf++) {
            bf16x8 b = *(const bf16x8*)(Bp + (size_t)(FULL * NF + nf) * 512 + lane * 8);
#pragma unroll
            for (int i = 0; i < 4; i++)
                acc[i][nf] = __builtin_amdgcn_mfma_f32_16x16x32_bf16(a[i], b, acc[i][nf], 0, 0, 0);
        }
    }

    // epilogue: within m-frag i, D row = quad*4 + ii, col = nf*16 + mrow
#pragma unroll
    for (int i = 0; i < 4; i++)
#pragma unroll
        for (int ii = 0; ii < 4; ii++) {
            const int r = m_base + i * 16 + quad * 4 + ii;
            if (r < M) {
#pragma unroll
                for (int nf = 0; nf < NF; nf++)
                    C[(size_t)r * NB + nf * 16 + mrow] = f32_to_bf16(acc[i][nf][ii]);
            }
        }
}

// ---------------------------------------------------------------------------
// Aggregation v3 (D=128, bf16->bf16): one wave/node, half-wave per edge,
// 16 edges/step: 8 contiguous ew loads in flight, then exec-masked row gathers
// (masked tail halves skip the fetch -> no padding BW waste).
// ---------------------------------------------------------------------------
__global__ __launch_bounds__(256) void aggregate128_v3(const uint2* __restrict__ h,
                                                       const float* __restrict__ dis,
                                                       const int* __restrict__ row_ptr,
                                                       const int2* __restrict__ ew,
                                                       const float* __restrict__ bias,
                                                       uint2* __restrict__ out, int n) {
    const int node = blockIdx.x * 4 + (threadIdx.x >> 6);
    if (node >= n) return;
    const int lane = threadIdx.x & 63;
    const int half = lane >> 5;
    const int c = lane & 31;  // uint2 index in row; channels 4c..4c+3
    const float di = dis[node];
    const int beg = row_ptr[node], end = row_ptr[node + 1];

    float ax0, ax1, ax2, ax3;
    {
        uint2 v = h[(size_t)node * 32 + c];
        float ws = half ? 0.f : di * di;  // self term counted once
        ax0 = ws * blo(v.x); ax1 = ws * bhi(v.x);
        ax2 = ws * blo(v.y); ax3 = ws * bhi(v.y);
    }
    for (int jb = beg; jb < end; jb += 16) {
        int2 p[8];
#pragma unroll
        for (int u = 0; u < 8; u++)
            p[u] = ew[min(jb + half + 2 * u, end - 1)];  // contiguous 8B, tail dup harmless
        float w[8];
        uint2 v[8];
#pragma unroll
        for (int u = 0; u < 8; u++) {
            const bool ok = (jb + half + 2 * u) < end;  // half-uniform -> exec-masked load
            w[u] = ok ? __builtin_bit_cast(float, p[u].y) : 0.f;
            if (ok) v[u] = h[(size_t)p[u].x * 32 + c];
            else    v[u] = make_uint2(0u, 0u);
        }
#pragma unroll
        for (int u = 0; u < 8; u++) {
            ax0 = fmaf(w[u], blo(v[u].x), ax0); ax1 = fmaf(w[u], bhi(v[u].x), ax1);
            ax2 = fmaf(w[u], blo(v[u].y), ax2); ax3 = fmaf(w[u], bhi(v[u].y), ax3);
        }
    }
    ax0 += __shfl_xor(ax0, 32);
    ax1 += __shfl_xor(ax1, 32);
    ax2 += __shfl_xor(ax2, 32);
    ax3 += __shfl_xor(ax3, 32);
    if (half == 0) {
        const float4 b = *(const float4*)(bias + 4 * c);
        uint2 r;
        r.x = (unsigned)f32_to_bf16(fmaxf(ax0 + b.x, 0.f)) |
              ((unsigned)f32_to_bf16(fmaxf(ax1 + b.y, 0.f)) << 16);
        r.y = (unsigned)f32_to_bf16(fmaxf(ax2 + b.z, 0.f)) |
              ((unsigned)f32_to_bf16(fmaxf(ax3 + b.w, 0.f)) << 16);
        out[(size_t)node * 32 + c] = r;
    }
}

// ---------------------------------------------------------------------------
// Aggregation v3 (D=64, bf16->fp32): one wave/node, quad per edge,
// 16 edges/step, same issue-then-gather structure.
// ---------------------------------------------------------------------------
__global__ __launch_bounds__(256) void aggregate64_v3(const uint2* __restrict__ h,
                                                      const float* __restrict__ dis,
                                                      const int* __restrict__ row_ptr,
                                                      const int2* __restrict__ ew,
                                                      const float* __restrict__ bias,
                                                      float4* __restrict__ out, int n) {
    const int node = blockIdx.x * 4 + (threadIdx.x >> 6);
    if (node >= n) return;
    const int lane = threadIdx.x & 63;
    const int quad = lane >> 4;
    const int c = lane & 15;  // uint2 index in row; channels 4c..4c+3
    const float di = dis[node];
    const int beg = row_ptr[node], end = row_ptr[node + 1];

    float ax0, ax1, ax2, ax3;
    {
        uint2 v = h[(size_t)node * 16 + c];
        float ws = quad ? 0.f : di * di;
        ax0 = ws * blo(v.x); ax1 = ws * bhi(v.x);
        ax2 = ws * blo(v.y); ax3 = ws * bhi(v.y);
    }
    for (int jb = beg; jb < end; jb += 16) {
        int2 p[4];
#pragma unroll
        for (int u = 0; u < 4; u++)
            p[u] = ew[min(jb + quad + 4 * u, end - 1)];
        float w[4];
        uint2 v[4];
#pragma unroll
        for (int u = 0; u < 4; u++) {
            const bool ok = (jb + quad + 4 * u) < end;  // quad-uniform
            w[u] = ok ? __builtin_bit_cast(float, p[u].y) : 0.f;
            if (ok) v[u] = h[(size_t)p[u].x * 16 + c];
            else    v[u] = make_uint2(0u, 0u);
        }
#pragma unroll
        for (int u = 0; u < 4; u++) {
            ax0 = fmaf(w[u], blo(v[u].x), ax0); ax1 = fmaf(w[u], bhi(v[u].x), ax1);
            ax2 = fmaf(w[u], blo(v[u].y), ax2); ax3 = fmaf(w[u], bhi(v[u].y), ax3);
        }
    }
    ax0 += __shfl_xor(ax0, 16); ax0 += __shfl_xor(ax0, 32);
    ax1 += __shfl_xor(ax1, 16); ax1 += __shfl_xor(ax1, 32);
    ax2 += __shfl_xor(ax2, 16); ax2 += __shfl_xor(ax2, 32);
    ax3 += __shfl_xor(ax3, 16); ax3 += __shfl_xor(ax3, 32);
    if (lane < 16) {
        const float4 b = *(const float4*)(bias + 4 * c);
        float4 r;
        r.x = fmaxf(ax0 + b.x, 0.f);
        r.y = fmaxf(ax1 + b.y, 0.f);
        r.z = fmaxf(ax2 + b.z, 0.f);
        r.w = fmaxf(ax3 + b.w, 0.f);
        out[(size_t)node * 16 + c] = r;
    }
}

// ---------------------------------------------------------------------------
// classifier: out[M x 10] = A[M x 64] * Wc[64 x 10] + bc. 16 threads/row.
// ---------------------------------------------------------------------------
__global__ __launch_bounds__(256) void classifier_kernel(const float* __restrict__ A,
                                                         const float* __restrict__ Wc,
                                                         const float* __restrict__ bc,
                                                         float* __restrict__ out, int M) {
    int idx = blockIdx.x * 256 + threadIdx.x;
    int row = idx >> 4;
    int c = idx & 15;
    if (row >= M || c >= CDIM) return;
    const float* a = A + (size_t)row * H2DIM;
    float acc = bc[c];
#pragma unroll 8
    for (int k = 0; k < H2DIM; k++) acc = fmaf(a[k], Wc[k * CDIM + c], acc);
    out[(size_t)row * CDIM + c] = acc;
}

// ---------------------------------------------------------------------------

extern "C" void kernel_launch(void* const* d_in, const int* in_sizes, int n_in,
                              void* d_out, int out_size, void* d_ws, size_t ws_size,
                              hipStream_t stream) {
    const float* x  = (const float*)d_in[0];
    const int*   ei = (const int*)d_in[1];
    const float* W1 = (const float*)d_in[2];
    const float* b1 = (const float*)d_in[3];
    const float* W2 = (const float*)d_in[4];
    const float* b2 = (const float*)d_in[5];
    const float* Wc = (const float*)d_in[6];
    const float* bc = (const float*)d_in[7];
    float* out = (float*)d_out;

    const int N = in_sizes[0] / FDIM;  // 100000
    const int E = in_sizes[1] / 2;     // 1600000
    const int* src = ei;
    const int* dst = ei + E;

    // workspace layout (bytes); agg2f overlays h1 (h1 dead after aggregate128)
    char* ws = (char*)d_ws;
    int*            cnt    = (int*)(ws + 0x000000);   // N ints (reused as cursor)
    int*            rowptr = (int*)(ws + 0x080000);   // N+1 ints
    float*          dis    = (float*)(ws + 0x100000); // N floats
    int*            bsums  = (int*)(ws + 0x180000);   // ceil(N/256) ints
    int2*           ew     = (int2*)(ws + 0x200000);  // E int2 (12.8 MB)
    unsigned short* W1p    = (unsigned short*)(ws + 0xE40000);  // 128 KB
    unsigned short* W2p    = (unsigned short*)(ws + 0xE80000);  // 16 KB
    unsigned short* h1     = (unsigned short*)(ws + 0xF00000);  // N*128 bf16 (25.6 MB)
    float*          agg2f  = (float*)(ws + 0xF00000);           // N*64 fp32 (overlays h1)
    unsigned short* agg1   = (unsigned short*)(ws + 0x2800000); // N*128 bf16 (25.6 MB)
    unsigned short* h2     = (unsigned short*)(ws + 0x4200000); // N*64 bf16 (12.8 MB)

    const int nb = (N + 255) / 256;

    // 1. CSR build + dis + per-edge weights
    hipMemsetAsync(cnt, 0, (size_t)N * sizeof(int), stream);
    hist_kernel<<<(E + 255) / 256, 256, 0, stream>>>(dst, cnt, E);
    dis_kernel<<<nb, 256, 0, stream>>>(cnt, dis, N);
    block_reduce_kernel<<<nb, 256, 0, stream>>>(cnt, bsums, N);
    scan_sums_kernel<<<1, 512, 0, stream>>>(bsums, nb, rowptr, N);
    scan_blocks_kernel<<<nb, 256, 0, stream>>>(cnt, bsums, rowptr, /*cursor=*/cnt, N);
    fill_kernel<<<(E + 255) / 256, 256, 0, stream>>>(src, dst, dis, /*cursor=*/cnt, ew, E);

    // 2. pack weights to MFMA B-fragment bf16 layout
    pack_w_kernel<<<(16 * 8 * 64 + 255) / 256, 256, 0, stream>>>(W1, W1p, FDIM, H1DIM, 16);
    pack_w_kernel<<<(4 * 4 * 64 + 255) / 256, 256, 0, stream>>>(W2, W2p, H1DIM, H2DIM, 4);

    const int gblocks = (N + 63) / 64;  // 1563, one wave / 64 rows each

    // 3. layer 1
    gemm_mfma<H1DIM, FDIM, false><<<gblocks, 64, 0, stream>>>(x, W1p, h1, N);
    aggregate128_v3<<<(N + 3) / 4, 256, 0, stream>>>((const uint2*)h1, dis, rowptr, ew, b1,
                                                     (uint2*)agg1, N);
    // 4. layer 2
    gemm_mfma<H2DIM, H1DIM, true><<<gblocks, 64, 0, stream>>>(agg1, W2p, h2, N);
    aggregate64_v3<<<(N + 3) / 4, 256, 0, stream>>>((const uint2*)h2, dis, rowptr, ew, b2,
                                                    (float4*)agg2f, N);

    // 5. classifier
    classifier_kernel<<<(N * 16 + 255) / 256, 256, 0, stream>>>(agg2f, Wc, bc, out, N);
}